// Round 8
// baseline (920.869 us; speedup 1.0000x reference)
//
#include <hip/hip_runtime.h>

typedef __bf16 bf16;
typedef __bf16 bf16x2 __attribute__((ext_vector_type(2)));
typedef __bf16 bf16x8 __attribute__((ext_vector_type(8)));
typedef float f32x4 __attribute__((ext_vector_type(4)));

#define AS1 __attribute__((address_space(1)))
#define AS3 __attribute__((address_space(3)))

__device__ __forceinline__ void gll16(const void* g, void* l) {
    __builtin_amdgcn_global_load_lds((const AS1 void*)g, (AS3 void*)l, 16, 0, 0);
}

// ---------------------------------------------------------------------------
// GEMM body: C[m][n] = epi( sum_k A[m][k]*W[n][k] ). Tile 256x128, BK=64,
// 8 waves, 512 threads, 3-buffer LDS ring (48KB/buf), XOR-swizzled LDS
// (8 slots/128B row -> conflict-free ds_read_b128), bijective XCD swizzle.
// STAGE=0: global_load_lds staging, counted vmcnt(6), raw s_barrier.
// STAGE=1: reg-staging (linear global dwordx4 -> swizzled ds_write_b128),
//          T14 issue-early/write-late, one __syncthreads per K-tile.
// Epilogue via swizzled bf16 LDS image -> full-sector vector stores.
// EPI: 0 plain bf16 | 1 bias+relu bf16 | 2 +dskip*U bf16 | 3 bias+softplus f32
// ---------------------------------------------------------------------------
template<int EPI, int STAGE>
__device__ __forceinline__
void gemm_body(const bf16* __restrict__ Abase, long long aBstride, int lda,
               const bf16* __restrict__ Wbase, long long wSstride,
               const float* __restrict__ biasBase, int biasStride,
               void* __restrict__ Cbase, long long cBstride, int ldc,
               const float* __restrict__ dskip,
               const bf16* __restrict__ Ubase, long long uBstride,
               const int* __restrict__ subj,
               int M, int K, int nbn, char* smem)
{
    const int tid = threadIdx.x;
    const int lane = tid & 63;
    const int wid = tid >> 6;
    const int wm = wid >> 1, wn = wid & 1;       // 4 x 2 wave grid
    const int l15 = lane & 15, lhi = lane >> 4;
    const int sw7 = l15 & 7;

    // bijective XCD-aware block swizzle (m204)
    const int nwg = gridDim.x;
    const int bid = blockIdx.x;
    const int q = nwg >> 3, r = nwg & 7;
    const int xcd = bid & 7;
    const int sw = xcd * q + (xcd < r ? xcd : r) + (bid >> 3);
    const int m0 = (sw / nbn) * 256;
    const int n0 = (sw % nbn) * 128;

    const int b = blockIdx.z;
    const int s = subj ? subj[b] : 0;
    const bf16* A = Abase + (size_t)b * aBstride;
    const bf16* W = Wbase + (size_t)s * wSstride;
    const float* bias = biasBase ? biasBase + (size_t)s * biasStride : nullptr;
    const bf16* U = Ubase ? Ubase + (size_t)b * uBstride : nullptr;
    const size_t coff = (size_t)b * cBstride;
    const int Mc = M - 1;

    f32x4 acc[4][4];
    #pragma unroll
    for (int i = 0; i < 4; ++i)
        #pragma unroll
        for (int j = 0; j < 4; ++j)
            acc[i][j] = f32x4{0.f, 0.f, 0.f, 0.f};

    int rA[4], rB[4];
    #pragma unroll
    for (int f = 0; f < 4; ++f) {
        rA[f] = (wm*64 + f*16 + l15) * 128;
        rB[f] = (wn*64 + f*16 + l15) * 128;
    }

    const int sub  = tid >> 3;     // 0..63 row within 64-row chunk
    const int slot = tid & 7;      // 16B slot within 128B row
    const int ldsw = (wid << 10);  // wave-uniform LDS offset (gll16 path)

    // --- STAGE 0: global_load_lds with pre-swizzled global source ---
    auto stage_lds = [&](int kt, int bufo) {
        #pragma unroll
        for (int c = 0; c < 4; ++c) {
            const int row = c*64 + sub;
            const int gk = (kt << 6) + ((slot ^ (row & 7)) << 3);
            int ar = m0 + row; if (ar > Mc) ar = Mc;
            gll16(A + (size_t)ar * lda + gk, smem + bufo + c*8192 + ldsw);
        }
        #pragma unroll
        for (int c = 0; c < 2; ++c) {
            const int row = c*64 + sub;
            const int gk = (kt << 6) + ((slot ^ (row & 7)) << 3);
            gll16(W + (size_t)(n0 + row) * K + gk, smem + bufo + 32768 + c*8192 + ldsw);
        }
    };

    // --- STAGE 1: reg-staging (linear global load, swizzled ds_write) ---
    float4 rgA[4], rgB[2];
    auto loadreg = [&](int kt) {
        #pragma unroll
        for (int c = 0; c < 4; ++c) {
            const int row = c*64 + sub;
            int ar = m0 + row; if (ar > Mc) ar = Mc;
            rgA[c] = *(const float4*)(A + (size_t)ar * lda + (kt << 6) + (slot << 3));
        }
        #pragma unroll
        for (int c = 0; c < 2; ++c)
            rgB[c] = *(const float4*)(W + (size_t)(n0 + c*64 + sub) * K + (kt << 6) + (slot << 3));
    };
    auto writereg = [&](int bufo) {
        const int wsl = sub*128 + ((slot ^ (sub & 7)) << 4);
        #pragma unroll
        for (int c = 0; c < 4; ++c)
            *(float4*)(smem + bufo + c*8192 + wsl) = rgA[c];
        #pragma unroll
        for (int c = 0; c < 2; ++c)
            *(float4*)(smem + bufo + 32768 + c*8192 + wsl) = rgB[c];
    };

    const int nkt = K >> 6;
    if constexpr (STAGE == 0) {
        stage_lds(0, 0);
        if (nkt > 1) stage_lds(1, 49152);
        asm volatile("s_waitcnt vmcnt(6)" ::: "memory");
        __builtin_amdgcn_s_barrier();
    } else {
        loadreg(0); writereg(0);
        loadreg(1); writereg(49152);
        __syncthreads();
    }

    int curo = 0, nno = 98304;
    for (int t = 0; t < nkt; ++t) {
        if constexpr (STAGE == 0) {
            if (t + 2 < nkt) stage_lds(t + 2, nno);
        } else {
            if (t + 2 < nkt) loadreg(t + 2);   // issue early, write late (T14)
        }

        const char* cb = smem + curo;
        #pragma unroll
        for (int kk = 0; kk < 2; ++kk) {
            const int so_ = (((kk << 2) | lhi) ^ sw7) << 4;
            bf16x8 af[4], bg[4];
            #pragma unroll
            for (int f = 0; f < 4; ++f) af[f] = *(const bf16x8*)(cb + rA[f] + so_);
            #pragma unroll
            for (int g = 0; g < 4; ++g) bg[g] = *(const bf16x8*)(cb + 32768 + rB[g] + so_);
            #pragma unroll
            for (int i = 0; i < 4; ++i)
                #pragma unroll
                for (int j = 0; j < 4; ++j)
                    acc[i][j] = __builtin_amdgcn_mfma_f32_16x16x32_bf16(
                        af[i], bg[j], acc[i][j], 0, 0, 0);
        }

        if constexpr (STAGE == 0) {
            if (t + 2 < nkt) {
                asm volatile("s_waitcnt vmcnt(6)" ::: "memory");
            } else if (t + 1 < nkt) {
                asm volatile("s_waitcnt vmcnt(0)" ::: "memory");
            }
            if (t + 1 < nkt) __builtin_amdgcn_s_barrier();
        } else {
            if (t + 2 < nkt) writereg(nno);
            if (t + 1 < nkt) __syncthreads();
        }

        curo = (curo == 98304) ? 0 : curo + 49152;
        nno  = (nno  == 98304) ? 0 : nno  + 49152;
    }

    // ---- epilogue: acc -> swizzled bf16 LDS image [256][128] -> vector IO ----
    __syncthreads();
    #pragma unroll
    for (int i = 0; i < 4; ++i) {
        #pragma unroll
        for (int j = 0; j < 4; ++j) {
            const int colb = (wn*64 + j*16 + l15) * 2;
            const f32x4 v = acc[i][j];
            #pragma unroll
            for (int qq = 0; qq < 4; ++qq) {
                const int row = wm*64 + i*16 + lhi*4 + qq;
                const int ad = row*256 + (colb & 15) + ((((colb >> 4) ^ (row & 7)) & 15) << 4);
                *(bf16*)(smem + ad) = (bf16)v[qq];
            }
        }
    }
    __syncthreads();

    #pragma unroll
    for (int u = 0; u < 8; ++u) {
        const int chunk = u*512 + tid;
        const int rr = chunk >> 4, ss = chunk & 15;
        const int gr = m0 + rr;
        if (gr >= M) continue;
        const int col = n0 + ss*8;
        const bf16x8 v = *(const bf16x8*)(smem + rr*256 + ((ss ^ (rr & 7)) << 4));
        if constexpr (EPI == 0) {
            const size_t ci = coff + (size_t)gr * ldc + col;
            *(bf16x8*)((bf16*)Cbase + ci) = v;
        } else if constexpr (EPI == 1) {
            const float4 b0 = *(const float4*)(bias + col);
            const float4 b1 = *(const float4*)(bias + col + 4);
            bf16x8 o;
            o[0] = (bf16)fmaxf((float)v[0] + b0.x, 0.f);
            o[1] = (bf16)fmaxf((float)v[1] + b0.y, 0.f);
            o[2] = (bf16)fmaxf((float)v[2] + b0.z, 0.f);
            o[3] = (bf16)fmaxf((float)v[3] + b0.w, 0.f);
            o[4] = (bf16)fmaxf((float)v[4] + b1.x, 0.f);
            o[5] = (bf16)fmaxf((float)v[5] + b1.y, 0.f);
            o[6] = (bf16)fmaxf((float)v[6] + b1.z, 0.f);
            o[7] = (bf16)fmaxf((float)v[7] + b1.w, 0.f);
            const size_t ci = coff + (size_t)gr * ldc + col;
            *(bf16x8*)((bf16*)Cbase + ci) = o;
        } else if constexpr (EPI == 2) {
            const bf16x8 uv = *(const bf16x8*)(U + (size_t)gr * ldc + col);
            const float4 d0 = *(const float4*)(dskip + col);
            const float4 d1 = *(const float4*)(dskip + col + 4);
            bf16x8 o;
            o[0] = (bf16)((float)v[0] + d0.x * (float)uv[0]);
            o[1] = (bf16)((float)v[1] + d0.y * (float)uv[1]);
            o[2] = (bf16)((float)v[2] + d0.z * (float)uv[2]);
            o[3] = (bf16)((float)v[3] + d0.w * (float)uv[3]);
            o[4] = (bf16)((float)v[4] + d1.x * (float)uv[4]);
            o[5] = (bf16)((float)v[5] + d1.y * (float)uv[5]);
            o[6] = (bf16)((float)v[6] + d1.z * (float)uv[6]);
            o[7] = (bf16)((float)v[7] + d1.w * (float)uv[7]);
            const size_t ci = coff + (size_t)gr * ldc + col;
            *(bf16x8*)((bf16*)Cbase + ci) = o;
        } else {
            const float4 b0 = *(const float4*)(bias + col);
            const float4 b1 = *(const float4*)(bias + col + 4);
            float xv[8];
            xv[0] = (float)v[0] + b0.x; xv[1] = (float)v[1] + b0.y;
            xv[2] = (float)v[2] + b0.z; xv[3] = (float)v[3] + b0.w;
            xv[4] = (float)v[4] + b1.x; xv[5] = (float)v[5] + b1.y;
            xv[6] = (float)v[6] + b1.z; xv[7] = (float)v[7] + b1.w;
            float4 o0, o1;
            #pragma unroll
            for (int e = 0; e < 8; ++e) {
                const float x = xv[e];
                // fast softplus: max(x,0) + log(1+exp(-|x|)) via v_exp/v_log
                const float sp = fmaxf(x, 0.f) + __logf(1.f + __expf(-fabsf(x)));
                if (e < 4) ((float*)&o0)[e] = sp; else ((float*)&o1)[e-4] = sp;
            }
            const size_t ci = coff + (size_t)gr * ldc + col;
            *(float4*)((float*)Cbase + ci) = o0;
            *(float4*)((float*)Cbase + ci + 4) = o1;
        }
    }
}

// named wrappers: en/dec keep gll16 (controls), bu/y use reg-staging (test)
#define GEMM_WRAP(NAME, EPI, STAGE)                                              \
__global__ __launch_bounds__(512, 2)                                             \
void NAME(const bf16* __restrict__ Abase, long long aBstride, int lda,           \
          const bf16* __restrict__ Wbase, long long wSstride,                    \
          const float* __restrict__ biasBase, int biasStride,                    \
          void* __restrict__ Cbase, long long cBstride, int ldc,                 \
          const float* __restrict__ dskip,                                       \
          const bf16* __restrict__ Ubase, long long uBstride,                    \
          const int* __restrict__ subj, int M, int K, int nbn)                   \
{                                                                                \
    __shared__ char smem[147456];                                                \
    gemm_body<EPI, STAGE>(Abase, aBstride, lda, Wbase, wSstride, biasBase,       \
                   biasStride, Cbase, cBstride, ldc, dskip, Ubase, uBstride,     \
                   subj, M, K, nbn, smem);                                       \
}
GEMM_WRAP(gemm_en,  1, 0)
GEMM_WRAP(gemm_bu,  0, 1)
GEMM_WRAP(gemm_y,   2, 1)
GEMM_WRAP(gemm_dec, 3, 0)

// ---------------------------------------------------------------------------
// Chunked LRU scan: T=1000 = 40 chunks x 25. Pair-vectorized: each thread
// owns channels (2h, 2h+1) -> 4B loads/stores instead of 2B scalars.
// ---------------------------------------------------------------------------
__global__ void scan_finals(const bf16* __restrict__ Bu,
                            const float* __restrict__ nu_log,
                            const float* __restrict__ theta_log,
                            float2* __restrict__ finals)
{
    const int g = blockIdx.x * 256 + threadIdx.x;   // 32*40*128
    const int hp = g & 127;
    const int c = (g >> 7) % 40;
    const int b = g / 5120;
    const int h0 = hp * 2;
    const float a0 = expf(nu_log[h0]),   t0 = expf(theta_log[h0]);
    const float a1 = expf(nu_log[h0+1]), t1 = expf(theta_log[h0+1]);
    const float m0_ = expf(-a0), m1_ = expf(-a1);
    const float lre0 = m0_*cosf(t0), lim0 = m0_*sinf(t0);
    const float lre1 = m1_*cosf(t1), lim1 = m1_*sinf(t1);
    float xr0 = 0.f, xi0 = 0.f, xr1 = 0.f, xi1 = 0.f;
    const bf16* p = Bu + ((size_t)(b*1000 + c*25)) * 512 + h0;
    for (int i = 0; i < 25; ++i) {
        const bf16x2 re = *(const bf16x2*)(p);
        const bf16x2 im = *(const bf16x2*)(p + 256);
        float nr = lre0*xr0 - lim0*xi0 + (float)re[0];
        float ni = lre0*xi0 + lim0*xr0 + (float)im[0];
        xr0 = nr; xi0 = ni;
        nr = lre1*xr1 - lim1*xi1 + (float)re[1];
        ni = lre1*xi1 + lim1*xr1 + (float)im[1];
        xr1 = nr; xi1 = ni;
        p += 512;
    }
    float4* fo = (float4*)&finals[(b*40 + c)*256 + h0];
    *fo = make_float4(xr0, xi0, xr1, xi1);
}

__global__ void scan_carry(const float2* __restrict__ finals,
                           float2* __restrict__ carry,
                           const float* __restrict__ nu_log,
                           const float* __restrict__ theta_log)
{
    const int g = blockIdx.x * 256 + threadIdx.x;   // 32*256
    const int h = g & 255;
    const int b = g >> 8;
    const float a  = expf(nu_log[h]);
    const float th = expf(theta_log[h]);
    const float mag = expf(-25.f * a);
    const float ang = 25.f * th;
    const float cre = mag * cosf(ang), cim = mag * sinf(ang);
    float pre = 0.f, pim = 0.f;
    for (int c = 0; c < 40; ++c) {
        const int idx = (b*40 + c)*256 + h;
        carry[idx] = make_float2(pre, pim);
        const float2 f = finals[idx];
        const float nre = f.x + cre*pre - cim*pim;
        const float nim = f.y + cre*pim + cim*pre;
        pre = nre; pim = nim;
    }
}

__global__ void scan_emit(const bf16* __restrict__ Bu,
                          const float2* __restrict__ carry,
                          const float* __restrict__ nu_log,
                          const float* __restrict__ theta_log,
                          bf16* __restrict__ xs)
{
    const int g = blockIdx.x * 256 + threadIdx.x;   // 32*40*128
    const int hp = g & 127;
    const int c = (g >> 7) % 40;
    const int b = g / 5120;
    const int h0 = hp * 2;
    const float a0 = expf(nu_log[h0]),   t0 = expf(theta_log[h0]);
    const float a1 = expf(nu_log[h0+1]), t1 = expf(theta_log[h0+1]);
    const float m0_ = expf(-a0), m1_ = expf(-a1);
    const float lre0 = m0_*cosf(t0), lim0 = m0_*sinf(t0);
    const float lre1 = m1_*cosf(t1), lim1 = m1_*sinf(t1);
    const float4 cr = *(const float4*)&carry[(b*40 + c)*256 + h0];
    float xr0 = cr.x, xi0 = cr.y, xr1 = cr.z, xi1 = cr.w;
    const bf16* p = Bu + ((size_t)(b*1000 + c*25)) * 512 + h0;
    bf16* qp = xs + ((size_t)(b*1000 + c*25)) * 512 + h0;
    for (int i = 0; i < 25; ++i) {
        const bf16x2 re = *(const bf16x2*)(p);
        const bf16x2 im = *(const bf16x2*)(p + 256);
        float nr = lre0*xr0 - lim0*xi0 + (float)re[0];
        float ni = lre0*xi0 + lim0*xr0 + (float)im[0];
        xr0 = nr; xi0 = ni;
        nr = lre1*xr1 - lim1*xi1 + (float)re[1];
        ni = lre1*xi1 + lim1*xr1 + (float)im[1];
        xr1 = nr; xi1 = ni;
        bf16x2 ro, io;
        ro[0] = (bf16)xr0; ro[1] = (bf16)xr1;
        io[0] = (bf16)xi0; io[1] = (bf16)xi1;
        *(bf16x2*)(qp) = ro;
        *(bf16x2*)(qp + 256) = io;
        p += 512; qp += 512;
    }
}

// ---------------------------------------------------------------------------
// small kernels
// ---------------------------------------------------------------------------
__global__ void cast8_kern(const float* __restrict__ src, bf16* __restrict__ dst, int n8)
{
    const int i = blockIdx.x * 256 + threadIdx.x;
    if (i >= n8) return;
    const float4* s = (const float4*)src + (size_t)i*2;
    const float4 v0 = s[0], v1 = s[1];
    bf16x8 o;
    o[0] = (bf16)v0.x; o[1] = (bf16)v0.y; o[2] = (bf16)v0.z; o[3] = (bf16)v0.w;
    o[4] = (bf16)v1.x; o[5] = (bf16)v1.y; o[6] = (bf16)v1.z; o[7] = (bf16)v1.w;
    *((bf16x8*)dst + i) = o;
}

__global__ void packWB_kern(const float* __restrict__ Bre, const float* __restrict__ Bim,
                            const float* __restrict__ glog, bf16* __restrict__ WB)
{
    const int idx = blockIdx.x * 256 + threadIdx.x;
    if (idx >= 4*512*768) return;
    const int l = idx / (512*768);
    const int r = idx - l*(512*768);
    const int n = r / 768;
    const int k = r - n*768;
    float v;
    if (n < 256) v = Bre[((size_t)(l*256 + n))*768 + k] * expf(glog[l*256 + n]);
    else         v = Bim[((size_t)(l*256 + (n-256)))*768 + k] * expf(glog[l*256 + (n-256)]);
    WB[idx] = (bf16)v;
}

__global__ void packWC_kern(const float* __restrict__ Cre, const float* __restrict__ Cim,
                            bf16* __restrict__ WC)
{
    const int idx = blockIdx.x * 256 + threadIdx.x;
    if (idx >= 4*768*512) return;
    const int l = idx / (768*512);
    const int r = idx - l*(768*512);
    const int o = r / 512;
    const int k = r - o*512;
    const float v = (k < 256) ? Cre[((size_t)(l*768 + o))*256 + k]
                              : -Cim[((size_t)(l*768 + o))*256 + (k - 256)];
    WC[idx] = (bf16)v;
}

__global__ void ctx_kern(const float* __restrict__ st, const int* __restrict__ sess,
                         const float* __restrict__ cW, const float* __restrict__ cb,
                         float* __restrict__ ctx)
{
    const int b = blockIdx.x;
    const int e = threadIdx.x;
    const int sid = sess[b];
    const float* r = st + (size_t)sid * 64;
    const float* w = cW + (size_t)e * 64;
    float acc = cb[e];
    #pragma unroll 8
    for (int i = 0; i < 64; ++i) acc += r[i] * w[i];
    ctx[b*256 + e] = fmaxf(acc, 0.f);
}

__global__ void ebctx_kern(const float* __restrict__ behav,
                           const float* __restrict__ bW,
                           const float* __restrict__ bB,
                           const int* __restrict__ subj,
                           const float* __restrict__ ctx,
                           bf16* __restrict__ h0)
{
    const int b  = blockIdx.x >> 3;
    const int tc = blockIdx.x & 7;
    const int e = threadIdx.x;
    const int s = subj[b];
    float wreg[16];
    const float* w = bW + ((size_t)(s*256) + e)*16;
    #pragma unroll
    for (int i = 0; i < 16; ++i) wreg[i] = w[i];
    const float bb_ = bB[s*256 + e];
    const bf16 cx = (bf16)ctx[b*256 + e];
    const int t0 = tc * 125;
    for (int t = t0; t < t0 + 125; ++t) {
        const int blk = b*1000 + t;
        const float* bi = behav + (size_t)blk * 16;
        float acc = bb_;
        #pragma unroll
        for (int i = 0; i < 16; ++i) acc += bi[i] * wreg[i];
        bf16* hp = h0 + (size_t)blk * 768;
        hp[256 + e] = (bf16)fmaxf(acc, 0.f);
        hp[512 + e] = cx;
    }
}

__global__ void predb_kern(const bf16* __restrict__ h, const float* __restrict__ W,
                           const float* __restrict__ bb, const int* __restrict__ subj,
                           float* __restrict__ out)
{
    const int lane = threadIdx.x & 63;
    const int wid  = threadIdx.x >> 6;
    const int row  = blockIdx.x * 4 + wid;   // < 32000
    const int b = row / 1000;
    const int s = subj[b];
    const bf16* hr = h + (size_t)row * 768;
    const float* w0 = W + (size_t)(s*2) * 768;
    const float* w1 = w0 + 768;
    float a0 = 0.f, a1 = 0.f;
    #pragma unroll
    for (int j = 0; j < 12; ++j) {
        const int idx = j*64 + lane;
        const float hv = (float)hr[idx];
        a0 += hv * w0[idx];
        a1 += hv * w1[idx];
    }
    #pragma unroll
    for (int m = 32; m >= 1; m >>= 1) {
        a0 += __shfl_xor(a0, m);
        a1 += __shfl_xor(a1, m);
    }
    if (lane == 0) {
        out[(size_t)row*2 + 0] = a0 + bb[s*2 + 0];
        out[(size_t)row*2 + 1] = a1 + bb[s*2 + 1];
    }
}

// ---------------------------------------------------------------------------
extern "C" void kernel_launch(void* const* d_in, const int* in_sizes, int n_in,
                              void* d_out, int out_size, void* d_ws, size_t ws_size,
                              hipStream_t stream)
{
    const float* neural_input   = (const float*)d_in[0];
    const float* behavior_input = (const float*)d_in[1];
    const int*   session_id     = (const int*)d_in[2];
    const int*   subject_id     = (const int*)d_in[3];
    const float* session_table  = (const float*)d_in[4];
    const float* neural_W  = (const float*)d_in[5];
    const float* neural_b  = (const float*)d_in[6];
    const float* behavior_W = (const float*)d_in[7];
    const float* behavior_b = (const float*)d_in[8];
    const float* ctx_W = (const float*)d_in[9];
    const float* ctx_b = (const float*)d_in[10];
    const float* nu_log    = (const float*)d_in[11];
    const float* theta_log = (const float*)d_in[12];
    const float* gamma_log = (const float*)d_in[13];
    const float* B_re = (const float*)d_in[14];
    const float* B_im = (const float*)d_in[15];
    const float* C_re = (const float*)d_in[16];
    const float* C_im = (const float*)d_in[17];
    const float* D_skip = (const float*)d_in[18];
    const float* dec_n_W = (const float*)d_in[19];
    const float* dec_n_b = (const float*)d_in[20];
    const float* dec_b_W = (const float*)d_in[21];
    const float* dec_b_b = (const float*)d_in[22];
    float* out = (float*)d_out;

    char* ws = (char*)d_ws;
    size_t off = 0;
    auto alloc = [&](size_t bytes) -> char* {
        char* p = ws + off;
        off += (bytes + 255) & ~(size_t)255;
        return p;
    };
    bf16*   Wn      = (bf16*)alloc((size_t)8*256*512*2);
    bf16*   Wd      = (bf16*)alloc((size_t)8*512*768*2);
    bf16*   WB      = (bf16*)alloc((size_t)4*512*768*2);
    bf16*   WC      = (bf16*)alloc((size_t)4*768*512*2);
    float*  ctxbuf  = (float*)alloc((size_t)32*256*4);
    bf16*   hA      = (bf16*)alloc((size_t)32*1000*768*2);
    bf16*   hB      = (bf16*)alloc((size_t)32*1000*768*2);
    bf16*   xs      = (bf16*)alloc((size_t)32*1000*512*2);
    float2* finals  = (float2*)alloc((size_t)32*40*256*8);
    float2* carry   = (float2*)alloc((size_t)32*40*256*8);
    bf16*   Bu      = (bf16*)alloc((size_t)32*1000*512*2);
    bf16*   nbf     = Bu;  // alias: neural bf16 consumed before Bu is written

    // --- weight prep / casts ---
    cast8_kern<<<dim3(512),   256, 0, stream>>>(neural_W, Wn, 131072);
    cast8_kern<<<dim3(1536),  256, 0, stream>>>(dec_n_W,  Wd, 393216);
    packWB_kern<<<dim3(6144), 256, 0, stream>>>(B_re, B_im, gamma_log, WB);
    packWC_kern<<<dim3(6144), 256, 0, stream>>>(C_re, C_im, WC);
    ctx_kern<<<dim3(32), 256, 0, stream>>>(session_table, session_id, ctx_W, ctx_b, ctxbuf);
    cast8_kern<<<dim3(8000), 256, 0, stream>>>(neural_input, nbf, 2048000);

    // --- front end: h0 = [relu(en) | relu(eb) | relu(ctx)] ---
    ebctx_kern<<<dim3(256), 256, 0, stream>>>(behavior_input, behavior_W, behavior_b,
                                              subject_id, ctxbuf, hA);
    gemm_en<<<dim3(8, 1, 32), 512, 0, stream>>>(
        nbf, 512000LL, 512, Wn, 131072LL, neural_b, 256,
        hA, 768000LL, 768, nullptr, nullptr, 0LL, subject_id, 1000, 512, 2);

    // --- 4 LRU layers ---
    for (int l = 0; l < 4; ++l) {
        const bf16* hin  = (l & 1) ? hB : hA;
        bf16*       hout = (l & 1) ? hA : hB;
        gemm_bu<<<dim3(500, 1, 1), 512, 0, stream>>>(
            hin, 0LL, 768, WB + (size_t)l*393216, 0LL, nullptr, 0,
            Bu, 0LL, 512, nullptr, nullptr, 0LL, nullptr, 32000, 768, 4);
        scan_finals<<<dim3(640), 256, 0, stream>>>(Bu, nu_log + l*256, theta_log + l*256, finals);
        scan_carry<<<dim3(32), 256, 0, stream>>>(finals, carry, nu_log + l*256, theta_log + l*256);
        scan_emit<<<dim3(640), 256, 0, stream>>>(Bu, carry, nu_log + l*256, theta_log + l*256, xs);
        gemm_y<<<dim3(750, 1, 1), 512, 0, stream>>>(
            xs, 0LL, 512, WC + (size_t)l*393216, 0LL, nullptr, 0,
            hout, 0LL, 768, D_skip + l*768, hin, 0LL, nullptr, 32000, 512, 6);
    }

    // --- decoders (final h is hA after 4 layers) ---
    gemm_dec<<<dim3(16, 1, 32), 512, 0, stream>>>(
        hA, 768000LL, 768, Wd, 393216LL, dec_n_b, 512,
        out, 512000LL, 512, nullptr, nullptr, 0LL, subject_id, 1000, 768, 4);
    predb_kern<<<dim3(8000), 256, 0, stream>>>(hA, dec_b_W, dec_b_b, subject_id,
                                               out + 16384000);
}

// Round 9
// 573.348 us; speedup vs baseline: 1.6061x; 1.6061x over previous
//
#include <hip/hip_runtime.h>

typedef __bf16 bf16;
typedef __bf16 bf16x2 __attribute__((ext_vector_type(2)));
typedef __bf16 bf16x8 __attribute__((ext_vector_type(8)));
typedef float f32x4 __attribute__((ext_vector_type(4)));

#define AS1 __attribute__((address_space(1)))
#define AS3 __attribute__((address_space(3)))

__device__ __forceinline__ void gll16(const void* g, void* l) {
    __builtin_amdgcn_global_load_lds((const AS1 void*)g, (AS3 void*)l, 16, 0, 0);
}

// ---------------------------------------------------------------------------
// GEMM body (round-3/7 proven config): C[m][n] = epi( sum_k A[m][k]*W[n][k] ).
// Tile 256x128, BK=64, 8 waves, 512 threads. 3-buffer LDS ring (48KB/buf),
// global_load_lds staging w/ pre-swizzled source, counted vmcnt(6), one
// s_barrier per K-tile, XOR-swizzled LDS (8 slots/128B row -> conflict-free
// ds_read_b128), bijective XCD swizzle. Epilogue via swizzled bf16 LDS image
// -> full-sector vector stores.
// EPI: 0 plain bf16 | 1 bias+relu bf16 | 2 +dskip*U bf16 | 3 bias+softplus f32
// ---------------------------------------------------------------------------
template<int EPI>
__device__ __forceinline__
void gemm_body(const bf16* __restrict__ Abase, long long aBstride, int lda,
               const bf16* __restrict__ Wbase, long long wSstride,
               const float* __restrict__ biasBase, int biasStride,
               void* __restrict__ Cbase, long long cBstride, int ldc,
               const float* __restrict__ dskip,
               const bf16* __restrict__ Ubase, long long uBstride,
               const int* __restrict__ subj,
               int M, int K, int nbn, char* smem)
{
    const int tid = threadIdx.x;
    const int lane = tid & 63;
    const int wid = tid >> 6;
    const int wm = wid >> 1, wn = wid & 1;       // 4 x 2 wave grid
    const int l15 = lane & 15, lhi = lane >> 4;
    const int sw7 = l15 & 7;

    // bijective XCD-aware block swizzle (m204)
    const int nwg = gridDim.x;
    const int bid = blockIdx.x;
    const int q = nwg >> 3, r = nwg & 7;
    const int xcd = bid & 7;
    const int sw = xcd * q + (xcd < r ? xcd : r) + (bid >> 3);
    const int m0 = (sw / nbn) * 256;
    const int n0 = (sw % nbn) * 128;

    const int b = blockIdx.z;
    const int s = subj ? subj[b] : 0;
    const bf16* A = Abase + (size_t)b * aBstride;
    const bf16* W = Wbase + (size_t)s * wSstride;
    const float* bias = biasBase ? biasBase + (size_t)s * biasStride : nullptr;
    const bf16* U = Ubase ? Ubase + (size_t)b * uBstride : nullptr;
    const size_t coff = (size_t)b * cBstride;
    const int Mc = M - 1;

    f32x4 acc[4][4];
    #pragma unroll
    for (int i = 0; i < 4; ++i)
        #pragma unroll
        for (int j = 0; j < 4; ++j)
            acc[i][j] = f32x4{0.f, 0.f, 0.f, 0.f};

    int rA[4], rB[4];
    #pragma unroll
    for (int f = 0; f < 4; ++f) {
        rA[f] = (wm*64 + f*16 + l15) * 128;
        rB[f] = (wn*64 + f*16 + l15) * 128;
    }

    const int sub  = tid >> 3;     // 0..63 row within 64-row chunk
    const int slot = tid & 7;      // 16B slot within 128B row
    const int ldsw = (wid << 10);  // wave-uniform LDS offset

    auto stage = [&](int kt, int bufo) {
        #pragma unroll
        for (int c = 0; c < 4; ++c) {           // A: 4 x 8KB chunks
            const int row = c*64 + sub;
            const int gk = (kt << 6) + ((slot ^ (row & 7)) << 3);
            int ar = m0 + row; if (ar > Mc) ar = Mc;
            gll16(A + (size_t)ar * lda + gk, smem + bufo + c*8192 + ldsw);
        }
        #pragma unroll
        for (int c = 0; c < 2; ++c) {           // B: 2 x 8KB chunks
            const int row = c*64 + sub;
            const int gk = (kt << 6) + ((slot ^ (row & 7)) << 3);
            gll16(W + (size_t)(n0 + row) * K + gk, smem + bufo + 32768 + c*8192 + ldsw);
        }
    };

    const int nkt = K >> 6;
    stage(0, 0);
    if (nkt > 1) stage(1, 49152);
    asm volatile("s_waitcnt vmcnt(6)" ::: "memory");
    __builtin_amdgcn_s_barrier();

    int curo = 0, nno = 98304;
    for (int t = 0; t < nkt; ++t) {
        if (t + 2 < nkt) stage(t + 2, nno);

        const char* cb = smem + curo;
        #pragma unroll
        for (int kk = 0; kk < 2; ++kk) {
            const int so_ = (((kk << 2) | lhi) ^ sw7) << 4;
            bf16x8 af[4], bg[4];
            #pragma unroll
            for (int f = 0; f < 4; ++f) af[f] = *(const bf16x8*)(cb + rA[f] + so_);
            #pragma unroll
            for (int g = 0; g < 4; ++g) bg[g] = *(const bf16x8*)(cb + 32768 + rB[g] + so_);
            #pragma unroll
            for (int i = 0; i < 4; ++i)
                #pragma unroll
                for (int j = 0; j < 4; ++j)
                    acc[i][j] = __builtin_amdgcn_mfma_f32_16x16x32_bf16(
                        af[i], bg[j], acc[i][j], 0, 0, 0);
        }

        if (t + 2 < nkt) {
            asm volatile("s_waitcnt vmcnt(6)" ::: "memory");   // tile t+1 landed
        } else if (t + 1 < nkt) {
            asm volatile("s_waitcnt vmcnt(0)" ::: "memory");   // tail drain
        }
        if (t + 1 < nkt) __builtin_amdgcn_s_barrier();

        curo = (curo == 98304) ? 0 : curo + 49152;
        nno  = (nno  == 98304) ? 0 : nno  + 49152;
    }

    // ---- epilogue: acc -> swizzled bf16 LDS image [256][128] -> vector IO ----
    __syncthreads();
    #pragma unroll
    for (int i = 0; i < 4; ++i) {
        #pragma unroll
        for (int j = 0; j < 4; ++j) {
            const int colb = (wn*64 + j*16 + l15) * 2;
            const f32x4 v = acc[i][j];
            #pragma unroll
            for (int qq = 0; qq < 4; ++qq) {
                const int row = wm*64 + i*16 + lhi*4 + qq;
                const int ad = row*256 + (colb & 15) + ((((colb >> 4) ^ (row & 7)) & 15) << 4);
                *(bf16*)(smem + ad) = (bf16)v[qq];
            }
        }
    }
    __syncthreads();

    #pragma unroll
    for (int u = 0; u < 8; ++u) {
        const int chunk = u*512 + tid;
        const int rr = chunk >> 4, ss = chunk & 15;
        const int gr = m0 + rr;
        if (gr >= M) continue;
        const int col = n0 + ss*8;
        const bf16x8 v = *(const bf16x8*)(smem + rr*256 + ((ss ^ (rr & 7)) << 4));
        if constexpr (EPI == 0) {
            const size_t ci = coff + (size_t)gr * ldc + col;
            *(bf16x8*)((bf16*)Cbase + ci) = v;
        } else if constexpr (EPI == 1) {
            const float4 b0 = *(const float4*)(bias + col);
            const float4 b1 = *(const float4*)(bias + col + 4);
            bf16x8 o;
            o[0] = (bf16)fmaxf((float)v[0] + b0.x, 0.f);
            o[1] = (bf16)fmaxf((float)v[1] + b0.y, 0.f);
            o[2] = (bf16)fmaxf((float)v[2] + b0.z, 0.f);
            o[3] = (bf16)fmaxf((float)v[3] + b0.w, 0.f);
            o[4] = (bf16)fmaxf((float)v[4] + b1.x, 0.f);
            o[5] = (bf16)fmaxf((float)v[5] + b1.y, 0.f);
            o[6] = (bf16)fmaxf((float)v[6] + b1.z, 0.f);
            o[7] = (bf16)fmaxf((float)v[7] + b1.w, 0.f);
            const size_t ci = coff + (size_t)gr * ldc + col;
            *(bf16x8*)((bf16*)Cbase + ci) = o;
        } else if constexpr (EPI == 2) {
            const bf16x8 uv = *(const bf16x8*)(U + (size_t)gr * ldc + col);
            const float4 d0 = *(const float4*)(dskip + col);
            const float4 d1 = *(const float4*)(dskip + col + 4);
            bf16x8 o;
            o[0] = (bf16)((float)v[0] + d0.x * (float)uv[0]);
            o[1] = (bf16)((float)v[1] + d0.y * (float)uv[1]);
            o[2] = (bf16)((float)v[2] + d0.z * (float)uv[2]);
            o[3] = (bf16)((float)v[3] + d0.w * (float)uv[3]);
            o[4] = (bf16)((float)v[4] + d1.x * (float)uv[4]);
            o[5] = (bf16)((float)v[5] + d1.y * (float)uv[5]);
            o[6] = (bf16)((float)v[6] + d1.z * (float)uv[6]);
            o[7] = (bf16)((float)v[7] + d1.w * (float)uv[7]);
            const size_t ci = coff + (size_t)gr * ldc + col;
            *(bf16x8*)((bf16*)Cbase + ci) = o;
        } else {
            const float4 b0 = *(const float4*)(bias + col);
            const float4 b1 = *(const float4*)(bias + col + 4);
            float xv[8];
            xv[0] = (float)v[0] + b0.x; xv[1] = (float)v[1] + b0.y;
            xv[2] = (float)v[2] + b0.z; xv[3] = (float)v[3] + b0.w;
            xv[4] = (float)v[4] + b1.x; xv[5] = (float)v[5] + b1.y;
            xv[6] = (float)v[6] + b1.z; xv[7] = (float)v[7] + b1.w;
            float4 o0, o1;
            #pragma unroll
            for (int e = 0; e < 8; ++e) {
                const float x = xv[e];
                // fast softplus via v_exp/v_log hw approx
                const float sp = fmaxf(x, 0.f) + __logf(1.f + __expf(-fabsf(x)));
                if (e < 4) ((float*)&o0)[e] = sp; else ((float*)&o1)[e-4] = sp;
            }
            const size_t ci = coff + (size_t)gr * ldc + col;
            *(float4*)((float*)Cbase + ci) = o0;
            *(float4*)((float*)Cbase + ci + 4) = o1;
        }
    }
}

// named wrappers for rocprof attribution (all gll16 staging)
#define GEMM_WRAP(NAME, EPI)                                                     \
__global__ __launch_bounds__(512, 2)                                             \
void NAME(const bf16* __restrict__ Abase, long long aBstride, int lda,           \
          const bf16* __restrict__ Wbase, long long wSstride,                    \
          const float* __restrict__ biasBase, int biasStride,                    \
          void* __restrict__ Cbase, long long cBstride, int ldc,                 \
          const float* __restrict__ dskip,                                       \
          const bf16* __restrict__ Ubase, long long uBstride,                    \
          const int* __restrict__ subj, int M, int K, int nbn)                   \
{                                                                                \
    __shared__ char smem[147456];                                                \
    gemm_body<EPI>(Abase, aBstride, lda, Wbase, wSstride, biasBase, biasStride,  \
                   Cbase, cBstride, ldc, dskip, Ubase, uBstride, subj,           \
                   M, K, nbn, smem);                                             \
}
GEMM_WRAP(gemm_en,  1)
GEMM_WRAP(gemm_bu,  0)
GEMM_WRAP(gemm_y,   2)
GEMM_WRAP(gemm_dec, 3)

// ---------------------------------------------------------------------------
// Chunked LRU scan: T=1000 = 40 chunks x 25. Pair-vectorized: each thread
// owns channels (2h, 2h+1) -> 4B loads/stores instead of 2B scalars.
// ---------------------------------------------------------------------------
__global__ void scan_finals(const bf16* __restrict__ Bu,
                            const float* __restrict__ nu_log,
                            const float* __restrict__ theta_log,
                            float2* __restrict__ finals)
{
    const int g = blockIdx.x * 256 + threadIdx.x;   // 32*40*128
    const int hp = g & 127;
    const int c = (g >> 7) % 40;
    const int b = g / 5120;
    const int h0 = hp * 2;
    const float a0 = expf(nu_log[h0]),   t0 = expf(theta_log[h0]);
    const float a1 = expf(nu_log[h0+1]), t1 = expf(theta_log[h0+1]);
    const float m0_ = expf(-a0), m1_ = expf(-a1);
    const float lre0 = m0_*cosf(t0), lim0 = m0_*sinf(t0);
    const float lre1 = m1_*cosf(t1), lim1 = m1_*sinf(t1);
    float xr0 = 0.f, xi0 = 0.f, xr1 = 0.f, xi1 = 0.f;
    const bf16* p = Bu + ((size_t)(b*1000 + c*25)) * 512 + h0;
    for (int i = 0; i < 25; ++i) {
        const bf16x2 re = *(const bf16x2*)(p);
        const bf16x2 im = *(const bf16x2*)(p + 256);
        float nr = lre0*xr0 - lim0*xi0 + (float)re[0];
        float ni = lre0*xi0 + lim0*xr0 + (float)im[0];
        xr0 = nr; xi0 = ni;
        nr = lre1*xr1 - lim1*xi1 + (float)re[1];
        ni = lre1*xi1 + lim1*xr1 + (float)im[1];
        xr1 = nr; xi1 = ni;
        p += 512;
    }
    float4* fo = (float4*)&finals[(b*40 + c)*256 + h0];
    *fo = make_float4(xr0, xi0, xr1, xi1);
}

__global__ void scan_carry(const float2* __restrict__ finals,
                           float2* __restrict__ carry,
                           const float* __restrict__ nu_log,
                           const float* __restrict__ theta_log)
{
    const int g = blockIdx.x * 256 + threadIdx.x;   // 32*256
    const int h = g & 255;
    const int b = g >> 8;
    const float a  = expf(nu_log[h]);
    const float th = expf(theta_log[h]);
    const float mag = expf(-25.f * a);
    const float ang = 25.f * th;
    const float cre = mag * cosf(ang), cim = mag * sinf(ang);
    float pre = 0.f, pim = 0.f;
    for (int c = 0; c < 40; ++c) {
        const int idx = (b*40 + c)*256 + h;
        carry[idx] = make_float2(pre, pim);
        const float2 f = finals[idx];
        const float nre = f.x + cre*pre - cim*pim;
        const float nim = f.y + cre*pim + cim*pre;
        pre = nre; pim = nim;
    }
}

__global__ void scan_emit(const bf16* __restrict__ Bu,
                          const float2* __restrict__ carry,
                          const float* __restrict__ nu_log,
                          const float* __restrict__ theta_log,
                          bf16* __restrict__ xs)
{
    const int g = blockIdx.x * 256 + threadIdx.x;   // 32*40*128
    const int hp = g & 127;
    const int c = (g >> 7) % 40;
    const int b = g / 5120;
    const int h0 = hp * 2;
    const float a0 = expf(nu_log[h0]),   t0 = expf(theta_log[h0]);
    const float a1 = expf(nu_log[h0+1]), t1 = expf(theta_log[h0+1]);
    const float m0_ = expf(-a0), m1_ = expf(-a1);
    const float lre0 = m0_*cosf(t0), lim0 = m0_*sinf(t0);
    const float lre1 = m1_*cosf(t1), lim1 = m1_*sinf(t1);
    const float4 cr = *(const float4*)&carry[(b*40 + c)*256 + h0];
    float xr0 = cr.x, xi0 = cr.y, xr1 = cr.z, xi1 = cr.w;
    const bf16* p = Bu + ((size_t)(b*1000 + c*25)) * 512 + h0;
    bf16* qp = xs + ((size_t)(b*1000 + c*25)) * 512 + h0;
    for (int i = 0; i < 25; ++i) {
        const bf16x2 re = *(const bf16x2*)(p);
        const bf16x2 im = *(const bf16x2*)(p + 256);
        float nr = lre0*xr0 - lim0*xi0 + (float)re[0];
        float ni = lre0*xi0 + lim0*xr0 + (float)im[0];
        xr0 = nr; xi0 = ni;
        nr = lre1*xr1 - lim1*xi1 + (float)re[1];
        ni = lre1*xi1 + lim1*xr1 + (float)im[1];
        xr1 = nr; xi1 = ni;
        bf16x2 ro, io;
        ro[0] = (bf16)xr0; ro[1] = (bf16)xr1;
        io[0] = (bf16)xi0; io[1] = (bf16)xi1;
        *(bf16x2*)(qp) = ro;
        *(bf16x2*)(qp + 256) = io;
        p += 512; qp += 512;
    }
}

// ---------------------------------------------------------------------------
// small kernels
// ---------------------------------------------------------------------------
__global__ void cast8_kern(const float* __restrict__ src, bf16* __restrict__ dst, int n8)
{
    const int i = blockIdx.x * 256 + threadIdx.x;
    if (i >= n8) return;
    const float4* s = (const float4*)src + (size_t)i*2;
    const float4 v0 = s[0], v1 = s[1];
    bf16x8 o;
    o[0] = (bf16)v0.x; o[1] = (bf16)v0.y; o[2] = (bf16)v0.z; o[3] = (bf16)v0.w;
    o[4] = (bf16)v1.x; o[5] = (bf16)v1.y; o[6] = (bf16)v1.z; o[7] = (bf16)v1.w;
    *((bf16x8*)dst + i) = o;
}

__global__ void packWB_kern(const float* __restrict__ Bre, const float* __restrict__ Bim,
                            const float* __restrict__ glog, bf16* __restrict__ WB)
{
    const int idx = blockIdx.x * 256 + threadIdx.x;
    if (idx >= 4*512*768) return;
    const int l = idx / (512*768);
    const int r = idx - l*(512*768);
    const int n = r / 768;
    const int k = r - n*768;
    float v;
    if (n < 256) v = Bre[((size_t)(l*256 + n))*768 + k] * expf(glog[l*256 + n]);
    else         v = Bim[((size_t)(l*256 + (n-256)))*768 + k] * expf(glog[l*256 + (n-256)]);
    WB[idx] = (bf16)v;
}

__global__ void packWC_kern(const float* __restrict__ Cre, const float* __restrict__ Cim,
                            bf16* __restrict__ WC)
{
    const int idx = blockIdx.x * 256 + threadIdx.x;
    if (idx >= 4*768*512) return;
    const int l = idx / (768*512);
    const int r = idx - l*(768*512);
    const int o = r / 512;
    const int k = r - o*512;
    const float v = (k < 256) ? Cre[((size_t)(l*768 + o))*256 + k]
                              : -Cim[((size_t)(l*768 + o))*256 + (k - 256)];
    WC[idx] = (bf16)v;
}

__global__ void ctx_kern(const float* __restrict__ st, const int* __restrict__ sess,
                         const float* __restrict__ cW, const float* __restrict__ cb,
                         float* __restrict__ ctx)
{
    const int b = blockIdx.x;
    const int e = threadIdx.x;
    const int sid = sess[b];
    const float* r = st + (size_t)sid * 64;
    const float* w = cW + (size_t)e * 64;
    float acc = cb[e];
    #pragma unroll 8
    for (int i = 0; i < 64; ++i) acc += r[i] * w[i];
    ctx[b*256 + e] = fmaxf(acc, 0.f);
}

__global__ void ebctx_kern(const float* __restrict__ behav,
                           const float* __restrict__ bW,
                           const float* __restrict__ bB,
                           const int* __restrict__ subj,
                           const float* __restrict__ ctx,
                           bf16* __restrict__ h0)
{
    const int b  = blockIdx.x >> 3;
    const int tc = blockIdx.x & 7;
    const int e = threadIdx.x;
    const int s = subj[b];
    float wreg[16];
    const float* w = bW + ((size_t)(s*256) + e)*16;
    #pragma unroll
    for (int i = 0; i < 16; ++i) wreg[i] = w[i];
    const float bb_ = bB[s*256 + e];
    const bf16 cx = (bf16)ctx[b*256 + e];
    const int t0 = tc * 125;
    for (int t = t0; t < t0 + 125; ++t) {
        const int blk = b*1000 + t;
        const float* bi = behav + (size_t)blk * 16;
        float acc = bb_;
        #pragma unroll
        for (int i = 0; i < 16; ++i) acc += bi[i] * wreg[i];
        bf16* hp = h0 + (size_t)blk * 768;
        hp[256 + e] = (bf16)fmaxf(acc, 0.f);
        hp[512 + e] = cx;
    }
}

__global__ void predb_kern(const bf16* __restrict__ h, const float* __restrict__ W,
                           const float* __restrict__ bb, const int* __restrict__ subj,
                           float* __restrict__ out)
{
    const int lane = threadIdx.x & 63;
    const int wid  = threadIdx.x >> 6;
    const int row  = blockIdx.x * 4 + wid;   // < 32000
    const int b = row / 1000;
    const int s = subj[b];
    const bf16* hr = h + (size_t)row * 768;
    const float* w0 = W + (size_t)(s*2) * 768;
    const float* w1 = w0 + 768;
    float a0 = 0.f, a1 = 0.f;
    #pragma unroll
    for (int j = 0; j < 12; ++j) {
        const int idx = j*64 + lane;
        const float hv = (float)hr[idx];
        a0 += hv * w0[idx];
        a1 += hv * w1[idx];
    }
    #pragma unroll
    for (int m = 32; m >= 1; m >>= 1) {
        a0 += __shfl_xor(a0, m);
        a1 += __shfl_xor(a1, m);
    }
    if (lane == 0) {
        out[(size_t)row*2 + 0] = a0 + bb[s*2 + 0];
        out[(size_t)row*2 + 1] = a1 + bb[s*2 + 1];
    }
}

// ---------------------------------------------------------------------------
extern "C" void kernel_launch(void* const* d_in, const int* in_sizes, int n_in,
                              void* d_out, int out_size, void* d_ws, size_t ws_size,
                              hipStream_t stream)
{
    const float* neural_input   = (const float*)d_in[0];
    const float* behavior_input = (const float*)d_in[1];
    const int*   session_id     = (const int*)d_in[2];
    const int*   subject_id     = (const int*)d_in[3];
    const float* session_table  = (const float*)d_in[4];
    const float* neural_W  = (const float*)d_in[5];
    const float* neural_b  = (const float*)d_in[6];
    const float* behavior_W = (const float*)d_in[7];
    const float* behavior_b = (const float*)d_in[8];
    const float* ctx_W = (const float*)d_in[9];
    const float* ctx_b = (const float*)d_in[10];
    const float* nu_log    = (const float*)d_in[11];
    const float* theta_log = (const float*)d_in[12];
    const float* gamma_log = (const float*)d_in[13];
    const float* B_re = (const float*)d_in[14];
    const float* B_im = (const float*)d_in[15];
    const float* C_re = (const float*)d_in[16];
    const float* C_im = (const float*)d_in[17];
    const float* D_skip = (const float*)d_in[18];
    const float* dec_n_W = (const float*)d_in[19];
    const float* dec_n_b = (const float*)d_in[20];
    const float* dec_b_W = (const float*)d_in[21];
    const float* dec_b_b = (const float*)d_in[22];
    float* out = (float*)d_out;

    char* ws = (char*)d_ws;
    size_t off = 0;
    auto alloc = [&](size_t bytes) -> char* {
        char* p = ws + off;
        off += (bytes + 255) & ~(size_t)255;
        return p;
    };
    bf16*   Wn      = (bf16*)alloc((size_t)8*256*512*2);
    bf16*   Wd      = (bf16*)alloc((size_t)8*512*768*2);
    bf16*   WB      = (bf16*)alloc((size_t)4*512*768*2);
    bf16*   WC      = (bf16*)alloc((size_t)4*768*512*2);
    float*  ctxbuf  = (float*)alloc((size_t)32*256*4);
    bf16*   hA      = (bf16*)alloc((size_t)32*1000*768*2);
    bf16*   hB      = (bf16*)alloc((size_t)32*1000*768*2);
    bf16*   xs      = (bf16*)alloc((size_t)32*1000*512*2);
    float2* finals  = (float2*)alloc((size_t)32*40*256*8);
    float2* carry   = (float2*)alloc((size_t)32*40*256*8);
    bf16*   Bu      = (bf16*)alloc((size_t)32*1000*512*2);
    bf16*   nbf     = Bu;  // alias: neural bf16 consumed before Bu is written

    // --- weight prep / casts ---
    cast8_kern<<<dim3(512),   256, 0, stream>>>(neural_W, Wn, 131072);
    cast8_kern<<<dim3(1536),  256, 0, stream>>>(dec_n_W,  Wd, 393216);
    packWB_kern<<<dim3(6144), 256, 0, stream>>>(B_re, B_im, gamma_log, WB);
    packWC_kern<<<dim3(6144), 256, 0, stream>>>(C_re, C_im, WC);
    ctx_kern<<<dim3(32), 256, 0, stream>>>(session_table, session_id, ctx_W, ctx_b, ctxbuf);
    cast8_kern<<<dim3(8000), 256, 0, stream>>>(neural_input, nbf, 2048000);

    // --- front end: h0 = [relu(en) | relu(eb) | relu(ctx)] ---
    ebctx_kern<<<dim3(256), 256, 0, stream>>>(behavior_input, behavior_W, behavior_b,
                                              subject_id, ctxbuf, hA);
    gemm_en<<<dim3(8, 1, 32), 512, 0, stream>>>(
        nbf, 512000LL, 512, Wn, 131072LL, neural_b, 256,
        hA, 768000LL, 768, nullptr, nullptr, 0LL, subject_id, 1000, 512, 2);

    // --- 4 LRU layers ---
    for (int l = 0; l < 4; ++l) {
        const bf16* hin  = (l & 1) ? hB : hA;
        bf16*       hout = (l & 1) ? hA : hB;
        gemm_bu<<<dim3(500, 1, 1), 512, 0, stream>>>(
            hin, 0LL, 768, WB + (size_t)l*393216, 0LL, nullptr, 0,
            Bu, 0LL, 512, nullptr, nullptr, 0LL, nullptr, 32000, 768, 4);
        scan_finals<<<dim3(640), 256, 0, stream>>>(Bu, nu_log + l*256, theta_log + l*256, finals);
        scan_carry<<<dim3(32), 256, 0, stream>>>(finals, carry, nu_log + l*256, theta_log + l*256);
        scan_emit<<<dim3(640), 256, 0, stream>>>(Bu, carry, nu_log + l*256, theta_log + l*256, xs);
        gemm_y<<<dim3(750, 1, 1), 512, 0, stream>>>(
            xs, 0LL, 512, WC + (size_t)l*393216, 0LL, nullptr, 0,
            hout, 0LL, 768, D_skip + l*768, hin, 0LL, nullptr, 32000, 512, 6);
    }

    // --- decoders (final h is hA after 4 layers) ---
    gemm_dec<<<dim3(16, 1, 32), 512, 0, stream>>>(
        hA, 768000LL, 768, Wd, 393216LL, dec_n_b, 512,
        out, 512000LL, 512, nullptr, nullptr, 0LL, subject_id, 1000, 768, 4);
    predb_kern<<<dim3(8000), 256, 0, stream>>>(hA, dec_b_W, dec_b_b, subject_id,
                                               out + 16384000);
}